// Round 4
// baseline (242.066 us; speedup 1.0000x reference)
//
#include <hip/hip_runtime.h>
#include <cstdint>
#include <cstddef>

#define EPSF 1e-8f
constexpr int HALF = 16384;
constexpr int KC   = 2048;

typedef __attribute__((ext_vector_type(8)))  short short8v;
typedef __attribute__((ext_vector_type(16))) float f32x16;
typedef float f32x4u __attribute__((ext_vector_type(4), aligned(4)));

__device__ __forceinline__ unsigned short f2bf_rn(float f) {
  unsigned u = __float_as_uint(f);
  return (unsigned short)((u + 0x7fffu + ((u >> 16) & 1u)) >> 16);
}
__device__ __forceinline__ float bf2f(unsigned short b) {
  return __uint_as_float(((unsigned)b) << 16);
}
__device__ __forceinline__ float wave_red_sum(float v) {
  #pragma unroll
  for (int m = 32; m; m >>= 1) v += __shfl_xor(v, m);
  return v;
}
__device__ __forceinline__ f32x16 z16() {
  f32x16 v;
  #pragma unroll
  for (int k = 0; k < 16; ++k) v[k] = 0.f;
  return v;
}

// ---------- prep: z (b,d,h,w) -> z_flat (n,d) fp32 ----------
__global__ __launch_bounds__(256) void prep_z_kernel(const float* __restrict__ z,
                                                     float* __restrict__ zf) {
  __shared__ float t[64][65];
  const int bi  = blockIdx.x >> 6;
  const int hw0 = (blockIdx.x & 63) << 6;
  const int tid = threadIdx.x;
  for (int i = tid; i < 4096; i += 256) {
    int d = i >> 6, j = i & 63;
    t[d][j] = z[bi * 262144 + d * 4096 + hw0 + j];
  }
  __syncthreads();
  for (int i = tid; i < 4096; i += 256) {
    int j = i >> 6, d = i & 63;
    zf[(bi * 4096 + hw0 + j) * 64 + d] = t[d][j];
  }
}

// ---------- prep: emb -> interleaved bf16 hi/lo (per col: 4 K-chunks x [16 hi][16 lo]) ----------
__global__ __launch_bounds__(256) void prep_emb_kernel(const float* __restrict__ emb,
    unsigned short* __restrict__ ebhl, float* __restrict__ embsq,
    double* __restrict__ accums) {
  const int c = blockIdx.x * 256 + threadIdx.x;
  if (blockIdx.x == 0 && threadIdx.x < 4) accums[threadIdx.x] = 0.0;
  float s = 0.f;
  unsigned short* dst = ebhl + c * 128;
  #pragma unroll
  for (int kc = 0; kc < 4; ++kc) {
    #pragma unroll
    for (int j = 0; j < 16; ++j) {
      float v = emb[c * 64 + kc * 16 + j];
      unsigned short hb = f2bf_rn(v);
      dst[kc * 32 + j]      = hb;
      dst[kc * 32 + 16 + j] = f2bf_rn(v - bf2f(hb));
      s = fmaf(v, v, s);
    }
  }
  embsq[c] = s;
}

// ---------- main: 1024 blocks x 256 thr (4 waves); block = 32 rows x 2048 cols ----------
// wave w: cols w*512..+511 as 4 chunks of 128; lane owns cols 4*l31+q (q=0..3) per chunk.
__global__ __launch_bounds__(256, 3) void main_kernel(
    const float* __restrict__ zf, const unsigned short* __restrict__ ebhl,
    const float* __restrict__ embsq, const float* __restrict__ emb,
    float* __restrict__ probs, int* __restrict__ minidx, double* __restrict__ accums)
{
  __shared__ float    red_es[32][4];
  __shared__ unsigned red_ak[32][4];
  __shared__ float    g_inv[32];
  __shared__ int      g_idx[32];
  __shared__ float    red_sc[3][4];

  const int tid = threadIdx.x;
  const int w = tid >> 6, lane = tid & 63;
  const int l31 = lane & 31, h = lane >> 5;
  const int n0 = blockIdx.x * 16;
  const int wc0 = w * 512;

  // A fragments: row = l31 (rows 0..15 = first half, 16..31 = second half), split fp32 -> bf16 hi/lo
  const int an = (l31 < 16) ? (n0 + l31) : (HALF + n0 + l31 - 16);
  const float* zrow = zf + an * 64;
  short8v Ah[4], Al[4];
  #pragma unroll
  for (int kc = 0; kc < 4; ++kc)
    #pragma unroll
    for (int j = 0; j < 8; ++j) {
      float v = zrow[kc * 16 + h * 8 + j];
      unsigned short hb = f2bf_rn(v);
      Ah[kc][j] = (short)hb;
      Al[kc][j] = (short)f2bf_rn(v - bf2f(hb));
    }

#define MFMA_CHUNK(c_)                                                          \
  {                                                                             \
    const unsigned short* bp = ebhl + (size_t)(wc0 + (c_) * 128 + (l31 << 2)) * 128 + h * 8; \
    _Pragma("unroll")                                                           \
    for (int kc = 0; kc < 4; ++kc) {                                            \
      const unsigned short* b = bp + kc * 32;                                   \
      short8v Bh0 = *(const short8v*)(b);                                       \
      short8v Bl0 = *(const short8v*)(b + 16);                                  \
      short8v Bh1 = *(const short8v*)(b + 128);                                 \
      short8v Bl1 = *(const short8v*)(b + 144);                                 \
      short8v Bh2 = *(const short8v*)(b + 256);                                 \
      short8v Bl2 = *(const short8v*)(b + 272);                                 \
      short8v Bh3 = *(const short8v*)(b + 384);                                 \
      short8v Bl3 = *(const short8v*)(b + 400);                                 \
      a0 = __builtin_amdgcn_mfma_f32_32x32x16_bf16(Ah[kc], Bh0, a0, 0, 0, 0);   \
      a0 = __builtin_amdgcn_mfma_f32_32x32x16_bf16(Al[kc], Bh0, a0, 0, 0, 0);   \
      a0 = __builtin_amdgcn_mfma_f32_32x32x16_bf16(Ah[kc], Bl0, a0, 0, 0, 0);   \
      a1 = __builtin_amdgcn_mfma_f32_32x32x16_bf16(Ah[kc], Bh1, a1, 0, 0, 0);   \
      a1 = __builtin_amdgcn_mfma_f32_32x32x16_bf16(Al[kc], Bh1, a1, 0, 0, 0);   \
      a1 = __builtin_amdgcn_mfma_f32_32x32x16_bf16(Ah[kc], Bl1, a1, 0, 0, 0);   \
      a2 = __builtin_amdgcn_mfma_f32_32x32x16_bf16(Ah[kc], Bh2, a2, 0, 0, 0);   \
      a2 = __builtin_amdgcn_mfma_f32_32x32x16_bf16(Al[kc], Bh2, a2, 0, 0, 0);   \
      a2 = __builtin_amdgcn_mfma_f32_32x32x16_bf16(Ah[kc], Bl2, a2, 0, 0, 0);   \
      a3 = __builtin_amdgcn_mfma_f32_32x32x16_bf16(Ah[kc], Bh3, a3, 0, 0, 0);   \
      a3 = __builtin_amdgcn_mfma_f32_32x32x16_bf16(Al[kc], Bh3, a3, 0, 0, 0);   \
      a3 = __builtin_amdgcn_mfma_f32_32x32x16_bf16(Ah[kc], Bl3, a3, 0, 0, 0);   \
    }                                                                           \
  }

  // ================= pass A: row sums of exp(s) + packed argmax =================
  float    es[16];
  unsigned ak[16];
  #pragma unroll
  for (int k = 0; k < 16; ++k) { es[k] = 0.f; ak[k] = 0u; }

  #pragma unroll
  for (int c = 0; c < 4; ++c) {
    f32x16 a0 = z16(), a1 = z16(), a2 = z16(), a3 = z16();
    MFMA_CHUNK(c)
    const int colb = wc0 + c * 128 + (l31 << 2);
    #pragma unroll
    for (int q = 0; q < 4; ++q) {
      const f32x16& aq = (q == 0) ? a0 : (q == 1) ? a1 : (q == 2) ? a2 : a3;
      const int col = colb + q;
      const float qq = embsq[col];
      const unsigned kinv = (unsigned)(2047 - col);
      #pragma unroll
      for (int k = 0; k < 16; ++k) {
        float s = fmaf(2.f, aq[k], -qq);      // softmax(-dist) == softmax(s)
        es[k] += __expf(s);
        unsigned u = __float_as_uint(s);
        u ^= (u & 0x80000000u) ? 0xFFFFFFFFu : 0x80000000u;   // order-preserving
        unsigned key = (u & 0xFFFFF800u) | kinv;              // tie -> lowest col
        ak[k] = key > ak[k] ? key : ak[k];
      }
    }
  }

  // in-wave reduce over l31 (h halves are distinct rows)
  #pragma unroll
  for (int k = 0; k < 16; ++k) {
    #pragma unroll
    for (int m = 1; m < 32; m <<= 1) {
      es[k] += __shfl_xor(es[k], m);
      unsigned o = (unsigned)__shfl_xor((int)ak[k], m);
      ak[k] = o > ak[k] ? o : ak[k];
    }
  }
  if (l31 == 0) {
    #pragma unroll
    for (int k = 0; k < 16; ++k) {
      int row = (k & 3) + 8 * (k >> 2) + 4 * h;
      red_es[row][w] = es[k];
      red_ak[row][w] = ak[k];
    }
  }
  __syncthreads();
  if (tid < 32) {
    float S = red_es[tid][0] + red_es[tid][1] + red_es[tid][2] + red_es[tid][3];
    unsigned K0 = red_ak[tid][0] > red_ak[tid][1] ? red_ak[tid][0] : red_ak[tid][1];
    unsigned K1 = red_ak[tid][2] > red_ak[tid][3] ? red_ak[tid][2] : red_ak[tid][3];
    unsigned K = K0 > K1 ? K0 : K1;
    g_inv[tid] = 1.f / S;
    int cbest = 2047 - (int)(K & 0x7FFu);
    g_idx[tid] = cbest;
    int n = (tid < 16) ? (n0 + tid) : (HALF + n0 + tid - 16);
    minidx[n] = cbest;
  }
  __syncthreads();

  // ================= pass B: recompute, normalize, store, JSD/entropy =================
  float vinv[16];
  #pragma unroll
  for (int k = 0; k < 16; ++k) vinv[k] = g_inv[(k & 3) + 8 * (k >> 2) + 4 * h];

  float tpl = 0.f, klm = 0.f;
  #pragma unroll
  for (int c = 0; c < 4; ++c) {
    f32x16 a0 = z16(), a1 = z16(), a2 = z16(), a3 = z16();
    MFMA_CHUNK(c)
    const int colb = wc0 + c * 128 + (l31 << 2);
    #pragma unroll
    for (int q = 0; q < 4; ++q) {
      f32x16& aq = (q == 0) ? a0 : (q == 1) ? a1 : (q == 2) ? a2 : a3;
      const float qq = embsq[colb + q];
      #pragma unroll
      for (int k = 0; k < 16; ++k)
        aq[k] = __expf(fmaf(2.f, aq[k], -qq)) * vinv[k];   // p
    }
    // dense float4 stores (dword-aligned; 32 lanes -> 512B contiguous per row-half)
    #pragma unroll
    for (int k = 0; k < 16; ++k) {
      int row = (k & 3) + 8 * (k >> 2) + 4 * h;
      int n = (row < 16) ? (n0 + row) : (HALF + n0 + row - 16);
      f32x4u v;
      v[0] = a0[k]; v[1] = a1[k]; v[2] = a2[k]; v[3] = a3[k];
      __builtin_nontemporal_store(v, (f32x4u*)(probs + (size_t)n * KC + colb));
    }
    // JSD/entropy partials: pair rows are regs (k, k+8)
    #pragma unroll
    for (int k = 0; k < 8; ++k) {
      float p1, p2, ps;
      p1 = a0[k]; p2 = a0[k + 8];
      tpl += p1 * __logf(p1 + EPSF) + p2 * __logf(p2 + EPSF);
      ps = p1 + p2; klm = fmaf(ps, __logf(fmaf(0.5f, ps, EPSF)), klm);
      p1 = a1[k]; p2 = a1[k + 8];
      tpl += p1 * __logf(p1 + EPSF) + p2 * __logf(p2 + EPSF);
      ps = p1 + p2; klm = fmaf(ps, __logf(fmaf(0.5f, ps, EPSF)), klm);
      p1 = a2[k]; p2 = a2[k + 8];
      tpl += p1 * __logf(p1 + EPSF) + p2 * __logf(p2 + EPSF);
      ps = p1 + p2; klm = fmaf(ps, __logf(fmaf(0.5f, ps, EPSF)), klm);
      p1 = a3[k]; p2 = a3[k + 8];
      tpl += p1 * __logf(p1 + EPSF) + p2 * __logf(p2 + EPSF);
      ps = p1 + p2; klm = fmaf(ps, __logf(fmaf(0.5f, ps, EPSF)), klm);
    }
  }

  // q_loss partial: (emb[argmin] - z)^2, block-wide coalesced
  float sq = 0.f;
  #pragma unroll
  for (int p = 0; p < 8; ++p) {
    int idx = tid + p * 256;
    int row = idx >> 6, d = idx & 63;
    int n = (row < 16) ? (n0 + row) : (HALF + n0 + row - 16);
    float diff = emb[g_idx[row] * 64 + d] - zf[n * 64 + d];
    sq = fmaf(diff, diff, sq);
  }

  tpl = wave_red_sum(tpl);
  klm = wave_red_sum(klm);
  sq  = wave_red_sum(sq);
  if (lane == 0) { red_sc[0][w] = tpl - klm; red_sc[1][w] = -tpl; red_sc[2][w] = sq; }
  __syncthreads();
  if (tid == 0) {
    float A = 0.f, B = 0.f, C = 0.f;
    #pragma unroll
    for (int i = 0; i < 4; ++i) { A += red_sc[0][i]; B += red_sc[1][i]; C += red_sc[2][i]; }
    atomicAdd(&accums[0], (double)A);   // sum over pairs (kl1+kl2)
    atomicAdd(&accums[1], (double)B);   // -(sum p ln p)  -> entropy
    atomicAdd(&accums[2], (double)C);   // sum sq diffs   -> q_loss
  }
#undef MFMA_CHUNK
}

// ---------- epilogue: z_q_out transpose-gather + scalar finalize ----------
__global__ __launch_bounds__(256) void zqout_kernel(const float* __restrict__ emb,
                                                    const int* __restrict__ minidx,
                                                    const double* __restrict__ accums,
                                                    float* __restrict__ out) {
  const int o  = blockIdx.x * 256 + threadIdx.x;
  const int w_ = o & 63;
  const int hh = (o >> 6) & 63;
  const int d  = (o >> 12) & 63;
  const int b  = o >> 18;
  const int n  = b * 4096 + hh * 64 + w_;
  out[o] = emb[minidx[n] * 64 + d];
  if (o == 0) {
    out[2097152] = (float)(1.25 * accums[2] / 2097152.0);   // q_loss
    out[2097153] = (float)(0.5 * accums[0] / 16384.0);      // jsd
    out[2097154] = (float)(accums[1] / 32768.0);            // entropy
  }
}

extern "C" void kernel_launch(void* const* d_in, const int* in_sizes, int n_in,
                              void* d_out, int out_size, void* d_ws, size_t ws_size,
                              hipStream_t stream) {
  const float* z   = (const float*)d_in[0];
  const float* emb = (const float*)d_in[1];
  float* out = (float*)d_out;

  float*          zf     = (float*)d_ws;                      // 8 MB
  unsigned short* ebhl   = (unsigned short*)(zf + 2097152);   // 512 KB
  float*          embsq  = (float*)(ebhl + 262144);           // 8 KB
  int*            minidx = (int*)(embsq + 2048);              // 128 KB
  double*         accums = (double*)(minidx + 32768);         // 32 B

  float* probs = out + 2097155;

  prep_z_kernel  <<<512,  256, 0, stream>>>(z, zf);
  prep_emb_kernel<<<8,    256, 0, stream>>>(emb, ebhl, embsq, accums);
  main_kernel    <<<1024, 256, 0, stream>>>(zf, ebhl, embsq, emb, probs, minidx, accums);
  zqout_kernel   <<<8192, 256, 0, stream>>>(emb, minidx, accums, out);
}

// Round 5
// 235.999 us; speedup vs baseline: 1.0257x; 1.0257x over previous
//
#include <hip/hip_runtime.h>
#include <cstdint>
#include <cstddef>

#define EPSF 1e-8f
constexpr int HALF = 16384;
constexpr int KC   = 2048;

typedef __attribute__((ext_vector_type(8)))  short short8v;
typedef __attribute__((ext_vector_type(16))) float f32x16;
typedef _Float16 h4v __attribute__((ext_vector_type(4)));

__device__ __forceinline__ unsigned short f2bf_rn(float f) {
  unsigned u = __float_as_uint(f);
  return (unsigned short)((u + 0x7fffu + ((u >> 16) & 1u)) >> 16);
}
__device__ __forceinline__ float bf2f(unsigned short b) {
  return __uint_as_float(((unsigned)b) << 16);
}
__device__ __forceinline__ float wave_red_sum(float v) {
  #pragma unroll
  for (int m = 32; m; m >>= 1) v += __shfl_xor(v, m);
  return v;
}
__device__ __forceinline__ f32x16 z16() {
  f32x16 v;
  #pragma unroll
  for (int k = 0; k < 16; ++k) v[k] = 0.f;
  return v;
}

// ---------- prep: z (b,d,h,w) -> z_flat (n,d) fp32 ----------
__global__ __launch_bounds__(256) void prep_z_kernel(const float* __restrict__ z,
                                                     float* __restrict__ zf) {
  __shared__ float t[64][65];
  const int bi  = blockIdx.x >> 6;
  const int hw0 = (blockIdx.x & 63) << 6;
  const int tid = threadIdx.x;
  for (int i = tid; i < 4096; i += 256) {
    int d = i >> 6, j = i & 63;
    t[d][j] = z[bi * 262144 + d * 4096 + hw0 + j];
  }
  __syncthreads();
  for (int i = tid; i < 4096; i += 256) {
    int j = i >> 6, d = i & 63;
    zf[(bi * 4096 + hw0 + j) * 64 + d] = t[d][j];
  }
}

// ---------- prep: emb -> interleaved bf16 hi/lo (per col: 4 K-chunks x [16 hi][16 lo]) ----------
__global__ __launch_bounds__(256) void prep_emb_kernel(const float* __restrict__ emb,
    unsigned short* __restrict__ ebhl, float* __restrict__ embsq,
    double* __restrict__ accums) {
  const int c = blockIdx.x * 256 + threadIdx.x;
  if (blockIdx.x == 0 && threadIdx.x < 4) accums[threadIdx.x] = 0.0;
  float s = 0.f;
  unsigned short* dst = ebhl + c * 128;
  #pragma unroll
  for (int kc = 0; kc < 4; ++kc) {
    #pragma unroll
    for (int j = 0; j < 16; ++j) {
      float v = emb[c * 64 + kc * 16 + j];
      unsigned short hb = f2bf_rn(v);
      dst[kc * 32 + j]      = hb;
      dst[kc * 32 + 16 + j] = f2bf_rn(v - bf2f(hb));
      s = fmaf(v, v, s);
    }
  }
  embsq[c] = s;
}

// ---------- kernel 1: scores s = 2*z.e - ||e||^2 -> fp16, uniform store duty ----------
// block = 16 pairs (32 rows) x 2048 cols; wave w: cols w*512..+511 (4 chunks of 128).
__global__ __launch_bounds__(256, 3) void score_kernel(
    const float* __restrict__ zf, const unsigned short* __restrict__ ebhl,
    const float* __restrict__ embsq, _Float16* __restrict__ sbuf,
    int pbase, int R)
{
  const int tid = threadIdx.x;
  const int w = tid >> 6, lane = tid & 63;
  const int l31 = lane & 31, h = lane >> 5;
  const int pl0 = blockIdx.x * 16;     // local pair base
  const int wc0 = w * 512;

  const int pg = pbase + pl0 + (l31 & 15);
  const int an = (l31 < 16) ? pg : (HALF + pg);
  const float* zrow = zf + an * 64;
  short8v Ah[4], Al[4];
  #pragma unroll
  for (int kc = 0; kc < 4; ++kc)
    #pragma unroll
    for (int j = 0; j < 8; ++j) {
      float v = zrow[kc * 16 + h * 8 + j];
      unsigned short hb = f2bf_rn(v);
      Ah[kc][j] = (short)hb;
      Al[kc][j] = (short)f2bf_rn(v - bf2f(hb));
    }

  #pragma unroll
  for (int c = 0; c < 4; ++c) {
    f32x16 a0 = z16(), a1 = z16(), a2 = z16(), a3 = z16();
    {
      const unsigned short* bp = ebhl + (size_t)(wc0 + c * 128 + (l31 << 2)) * 128 + h * 8;
      #pragma unroll
      for (int kc = 0; kc < 4; ++kc) {
        const unsigned short* b = bp + kc * 32;
        short8v Bh0 = *(const short8v*)(b);
        short8v Bl0 = *(const short8v*)(b + 16);
        short8v Bh1 = *(const short8v*)(b + 128);
        short8v Bl1 = *(const short8v*)(b + 144);
        short8v Bh2 = *(const short8v*)(b + 256);
        short8v Bl2 = *(const short8v*)(b + 272);
        short8v Bh3 = *(const short8v*)(b + 384);
        short8v Bl3 = *(const short8v*)(b + 400);
        a0 = __builtin_amdgcn_mfma_f32_32x32x16_bf16(Ah[kc], Bh0, a0, 0, 0, 0);
        a0 = __builtin_amdgcn_mfma_f32_32x32x16_bf16(Al[kc], Bh0, a0, 0, 0, 0);
        a0 = __builtin_amdgcn_mfma_f32_32x32x16_bf16(Ah[kc], Bl0, a0, 0, 0, 0);
        a1 = __builtin_amdgcn_mfma_f32_32x32x16_bf16(Ah[kc], Bh1, a1, 0, 0, 0);
        a1 = __builtin_amdgcn_mfma_f32_32x32x16_bf16(Al[kc], Bh1, a1, 0, 0, 0);
        a1 = __builtin_amdgcn_mfma_f32_32x32x16_bf16(Ah[kc], Bl1, a1, 0, 0, 0);
        a2 = __builtin_amdgcn_mfma_f32_32x32x16_bf16(Ah[kc], Bh2, a2, 0, 0, 0);
        a2 = __builtin_amdgcn_mfma_f32_32x32x16_bf16(Al[kc], Bh2, a2, 0, 0, 0);
        a2 = __builtin_amdgcn_mfma_f32_32x32x16_bf16(Ah[kc], Bl2, a2, 0, 0, 0);
        a3 = __builtin_amdgcn_mfma_f32_32x32x16_bf16(Ah[kc], Bh3, a3, 0, 0, 0);
        a3 = __builtin_amdgcn_mfma_f32_32x32x16_bf16(Al[kc], Bh3, a3, 0, 0, 0);
        a3 = __builtin_amdgcn_mfma_f32_32x32x16_bf16(Ah[kc], Bl3, a3, 0, 0, 0);
      }
    }
    const int colb = wc0 + c * 128 + (l31 << 2);
    const float4 q4 = *(const float4*)(embsq + colb);
    #pragma unroll
    for (int k = 0; k < 16; ++k) {
      a0[k] = fmaf(2.f, a0[k], -q4.x);
      a1[k] = fmaf(2.f, a1[k], -q4.y);
      a2[k] = fmaf(2.f, a2[k], -q4.z);
      a3[k] = fmaf(2.f, a3[k], -q4.w);
    }
    #pragma unroll
    for (int k = 0; k < 16; ++k) {
      int row = (k & 3) + 8 * (k >> 2) + 4 * h;
      int lrow = (row < 16) ? (pl0 + row) : (R + pl0 + row - 16);
      h4v hv;
      hv[0] = (_Float16)a0[k]; hv[1] = (_Float16)a1[k];
      hv[2] = (_Float16)a2[k]; hv[3] = (_Float16)a3[k];
      *(h4v*)(sbuf + (size_t)lrow * KC + colb) = hv;
    }
  }
}

// ---------- kernel 2: softmax-normalize + argmax + probs store + JSD/entropy/q_loss ----------
// block = 8 pairs (16 rows) x 2048 cols; thread owns cols {tid + 256*c} (lane-dense stores).
__global__ __launch_bounds__(256, 4) void norm_kernel(
    const _Float16* __restrict__ sbuf, const float* __restrict__ zf,
    const float* __restrict__ emb, float* __restrict__ probs,
    int* __restrict__ minidx, double* __restrict__ accums, int pbase, int R)
{
  __shared__ float    SpW[16][4];
  __shared__ unsigned KpW[16][4];
  __shared__ float    g_inv[16];
  __shared__ int      g_idx[16];
  __shared__ float    red_sc[3][4];

  const int tid = threadIdx.x;
  const int w = tid >> 6, lane = tid & 63;
  const int q0 = blockIdx.x * 8;     // local pair base

  // ---- pass 1: S = sum exp(s) + packed argmax per row
  float Sj[16]; unsigned Kj[16];
  #pragma unroll
  for (int j = 0; j < 16; ++j) {
    const int lrow = (j < 8) ? (q0 + j) : (R + q0 + j - 8);
    const _Float16* sp = sbuf + (size_t)lrow * KC;
    float S = 0.f; unsigned key = 0u;
    #pragma unroll
    for (int c = 0; c < 8; ++c) {
      int col = tid + (c << 8);
      float f = (float)sp[col];
      S += __expf(f);
      unsigned u = __float_as_uint(f);
      u ^= (unsigned)((int)u >> 31) | 0x80000000u;      // order-preserving
      unsigned key2 = (u & 0xFFFFF800u) | (unsigned)(2047 - col);  // tie -> low col
      key = key2 > key ? key2 : key;
    }
    Sj[j] = S; Kj[j] = key;
  }
  #pragma unroll
  for (int j = 0; j < 16; ++j) {
    #pragma unroll
    for (int m = 1; m < 64; m <<= 1) {
      Sj[j] += __shfl_xor(Sj[j], m);
      unsigned o = (unsigned)__shfl_xor((int)Kj[j], m);
      Kj[j] = o > Kj[j] ? o : Kj[j];
    }
  }
  if (lane == 0) {
    #pragma unroll
    for (int j = 0; j < 16; ++j) { SpW[j][w] = Sj[j]; KpW[j][w] = Kj[j]; }
  }
  __syncthreads();
  if (tid < 16) {
    float S = SpW[tid][0] + SpW[tid][1] + SpW[tid][2] + SpW[tid][3];
    unsigned K0 = KpW[tid][0] > KpW[tid][1] ? KpW[tid][0] : KpW[tid][1];
    unsigned K1 = KpW[tid][2] > KpW[tid][3] ? KpW[tid][2] : KpW[tid][3];
    unsigned K = K0 > K1 ? K0 : K1;
    g_inv[tid] = 1.f / S;
    int ci = 2047 - (int)(K & 0x7FFu);
    g_idx[tid] = ci;
    int n = (tid < 8) ? (pbase + q0 + tid) : (HALF + pbase + q0 + tid - 8);
    minidx[n] = ci;
  }
  __syncthreads();

  // ---- pass 2: p = exp(s)/S, dense scalar stores, JSD/entropy partials
  float tpl = 0.f, klm = 0.f;
  #pragma unroll
  for (int i = 0; i < 8; ++i) {
    const float invL = g_inv[i], invH = g_inv[i + 8];
    const _Float16* sl = sbuf + (size_t)(q0 + i) * KC;
    const _Float16* sh = sbuf + (size_t)(R + q0 + i) * KC;
    const size_t plo = (size_t)(pbase + q0 + i) * KC;
    const size_t phi = plo + (size_t)HALF * KC;
    #pragma unroll
    for (int c = 0; c < 8; ++c) {
      int col = tid + (c << 8);
      float p1 = __expf((float)sl[col]) * invL;
      float p2 = __expf((float)sh[col]) * invH;
      __builtin_nontemporal_store(p1, probs + plo + col);
      __builtin_nontemporal_store(p2, probs + phi + col);
      tpl += p1 * __logf(p1 + EPSF) + p2 * __logf(p2 + EPSF);
      float ps = p1 + p2;
      klm = fmaf(ps, __logf(fmaf(0.5f, ps, EPSF)), klm);
    }
  }

  // ---- q_loss partial: (emb[argmin] - z)^2 over 16 rows x 64 dims
  float sq = 0.f;
  #pragma unroll
  for (int p = 0; p < 4; ++p) {
    int item = tid + (p << 8);
    int j = item >> 6, d = item & 63;
    int n = (j < 8) ? (pbase + q0 + j) : (HALF + pbase + q0 + j - 8);
    float diff = emb[g_idx[j] * 64 + d] - zf[n * 64 + d];
    sq = fmaf(diff, diff, sq);
  }

  tpl = wave_red_sum(tpl);
  klm = wave_red_sum(klm);
  sq  = wave_red_sum(sq);
  if (lane == 0) { red_sc[0][w] = tpl - klm; red_sc[1][w] = -tpl; red_sc[2][w] = sq; }
  __syncthreads();
  if (tid == 0) {
    float A = 0.f, B = 0.f, C = 0.f;
    #pragma unroll
    for (int i = 0; i < 4; ++i) { A += red_sc[0][i]; B += red_sc[1][i]; C += red_sc[2][i]; }
    atomicAdd(&accums[0], (double)A);   // sum over pairs (kl1+kl2)
    atomicAdd(&accums[1], (double)B);   // -(sum p ln p) -> entropy
    atomicAdd(&accums[2], (double)C);   // sum sq diffs  -> q_loss
  }
}

// ---------- epilogue: z_q_out transpose-gather + scalar finalize ----------
__global__ __launch_bounds__(256) void zqout_kernel(const float* __restrict__ emb,
                                                    const int* __restrict__ minidx,
                                                    const double* __restrict__ accums,
                                                    float* __restrict__ out) {
  const int o  = blockIdx.x * 256 + threadIdx.x;
  const int w_ = o & 63;
  const int hh = (o >> 6) & 63;
  const int d  = (o >> 12) & 63;
  const int b  = o >> 18;
  const int n  = b * 4096 + hh * 64 + w_;
  out[o] = emb[minidx[n] * 64 + d];
  if (o == 0) {
    out[2097152] = (float)(1.25 * accums[2] / 2097152.0);   // q_loss
    out[2097153] = (float)(0.5 * accums[0] / 16384.0);      // jsd
    out[2097154] = (float)(accums[1] / 32768.0);            // entropy
  }
}

extern "C" void kernel_launch(void* const* d_in, const int* in_sizes, int n_in,
                              void* d_out, int out_size, void* d_ws, size_t ws_size,
                              hipStream_t stream) {
  const float* z   = (const float*)d_in[0];
  const float* emb = (const float*)d_in[1];
  float* out = (float*)d_out;

  float*          zf     = (float*)d_ws;                      // 8 MB
  unsigned short* ebhl   = (unsigned short*)(zf + 2097152);   // 512 KB
  float*          embsq  = (float*)(ebhl + 262144);           // 8 KB
  int*            minidx = (int*)(embsq + 2048);              // 128 KB
  double*         accums = (double*)(minidx + 32768);         // 32 B

  size_t used = (size_t)((char*)(accums + 4) - (char*)d_ws);
  size_t off  = (used + 255) & ~(size_t)255;
  _Float16* sbuf = (_Float16*)((char*)d_ws + off);
  size_t avail = (ws_size > off) ? (ws_size - off) : 0;
  long Rmax = (long)(avail / (2 * KC * sizeof(_Float16) * 2));  // bytes per pair = 8192
  int R = (Rmax >= HALF) ? HALF : (int)(Rmax & ~15L);
  if (R < 16) R = 16;   // last-resort; needs ws >= ~9.2 MB

  float* probs = out + 2097155;

  prep_z_kernel  <<<512, 256, 0, stream>>>(z, zf);
  prep_emb_kernel<<<8,   256, 0, stream>>>(emb, ebhl, embsq, accums);
  for (int pbase = 0; pbase < HALF; pbase += R) {
    int Rs = (HALF - pbase < R) ? (HALF - pbase) : R;
    score_kernel<<<Rs / 16, 256, 0, stream>>>(zf, ebhl, embsq, sbuf, pbase, Rs);
    norm_kernel <<<Rs / 8,  256, 0, stream>>>(sbuf, zf, emb, probs, minidx, accums, pbase, Rs);
  }
  zqout_kernel   <<<8192, 256, 0, stream>>>(emb, minidx, accums, out);
}

// Round 6
// 214.001 us; speedup vs baseline: 1.1311x; 1.1028x over previous
//
#include <hip/hip_runtime.h>
#include <cstdint>
#include <cstddef>

#define EPSF 1e-8f
constexpr int HALF = 16384;
constexpr int KC   = 2048;

typedef __attribute__((ext_vector_type(8)))  short short8v;
typedef __attribute__((ext_vector_type(16))) float f32x16;
typedef _Float16 h4v __attribute__((ext_vector_type(4)));

__device__ __forceinline__ unsigned short f2bf_rn(float f) {
  unsigned u = __float_as_uint(f);
  return (unsigned short)((u + 0x7fffu + ((u >> 16) & 1u)) >> 16);
}
__device__ __forceinline__ float wave_red_sum(float v) {
  #pragma unroll
  for (int m = 32; m; m >>= 1) v += __shfl_xor(v, m);
  return v;
}
__device__ __forceinline__ f32x16 z16() {
  f32x16 v;
  #pragma unroll
  for (int k = 0; k < 16; ++k) v[k] = 0.f;
  return v;
}

// ---------- prep (merged): blocks 0-511: z transpose; 512-519: emb pack ----------
// ebh fragment-order layout: for col C, k K: tile=C>>7, l31=(C&127)>>2, q=C&3,
// kc=K>>4, h=(K>>3)&1, j=K&7 -> flat = tile*8192 + (q*4+kc)*512 + h*256 + l31*8 + j.
// Then a wave's B-load for fixed (q,kc,h) is 32 lanes x 16B contiguous = 512B dense.
__global__ __launch_bounds__(256) void prep_kernel(const float* __restrict__ z,
    const float* __restrict__ emb, float* __restrict__ zf,
    unsigned short* __restrict__ ebh, float* __restrict__ embsq,
    double* __restrict__ accums) {
  const int tid = threadIdx.x;
  if (blockIdx.x < 512) {
    __shared__ float t[64][65];
    const int bi  = blockIdx.x >> 6;
    const int hw0 = (blockIdx.x & 63) << 6;
    for (int i = tid; i < 4096; i += 256) {
      int d = i >> 6, j = i & 63;
      t[d][j] = z[bi * 262144 + d * 4096 + hw0 + j];
    }
    __syncthreads();
    for (int i = tid; i < 4096; i += 256) {
      int j = i >> 6, d = i & 63;
      zf[(bi * 4096 + hw0 + j) * 64 + d] = t[d][j];
    }
  } else {
    if (blockIdx.x == 512 && tid < 4) accums[tid] = 0.0;
    const int c = (blockIdx.x - 512) * 256 + tid;
    const int tile = c >> 7, l31c = (c & 127) >> 2, q = c & 3;
    unsigned short* base = ebh + tile * 8192 + l31c * 8;
    float s = 0.f;
    #pragma unroll
    for (int kc = 0; kc < 4; ++kc) {
      unsigned short* seg = base + (q * 4 + kc) * 512;
      #pragma unroll
      for (int j = 0; j < 16; ++j) {
        float v = emb[c * 64 + kc * 16 + j];
        seg[(j >> 3) * 256 + (j & 7)] = f2bf_rn(v);
        s = fmaf(v, v, s);
      }
    }
    embsq[c] = s;
  }
}

// ---------- score: s = 2*z.e - ||e||^2 (bf16 MFMA) -> sbuf fp16; S, argmax, q_loss ----------
// 1024 blocks x 256 thr; block = 16 pairs (32 rows) x 2048 cols; wave w: 512 cols.
__global__ __launch_bounds__(256, 3) void score_kernel(
    const float* __restrict__ zf, const unsigned short* __restrict__ ebh,
    const float* __restrict__ embsq, const float* __restrict__ emb,
    _Float16* __restrict__ sbuf, float* __restrict__ Sinv,
    int* __restrict__ minidx, double* __restrict__ accums)
{
  __shared__ float    red_es[32][4];
  __shared__ unsigned red_ak[32][4];
  __shared__ int      g_idx[32];
  __shared__ float    red_q[4];

  const int tid = threadIdx.x;
  const int w = tid >> 6, lane = tid & 63;
  const int l31 = lane & 31, h = lane >> 5;
  const int n0 = blockIdx.x * 16;
  const int wc0 = w * 512;

  // A fragments (bf16 hi only): row = l31
  const int an = (l31 < 16) ? (n0 + l31) : (HALF + n0 + l31 - 16);
  const float* zrow = zf + an * 64;
  short8v Ah[4];
  #pragma unroll
  for (int kc = 0; kc < 4; ++kc)
    #pragma unroll
    for (int j = 0; j < 8; ++j)
      Ah[kc][j] = (short)f2bf_rn(zrow[kc * 16 + h * 8 + j]);

  float    es[16];
  unsigned ak[16];
  #pragma unroll
  for (int k = 0; k < 16; ++k) { es[k] = 0.f; ak[k] = 0u; }

  #pragma unroll
  for (int c = 0; c < 4; ++c) {
    f32x16 a0 = z16(), a1 = z16(), a2 = z16(), a3 = z16();
    const unsigned short* bp = ebh + (size_t)(wc0 / 128 + c) * 8192 + h * 256 + l31 * 8;
    #pragma unroll
    for (int kc = 0; kc < 4; ++kc) {
      short8v B0 = *(const short8v*)(bp + (0 * 4 + kc) * 512);
      short8v B1 = *(const short8v*)(bp + (1 * 4 + kc) * 512);
      short8v B2 = *(const short8v*)(bp + (2 * 4 + kc) * 512);
      short8v B3 = *(const short8v*)(bp + (3 * 4 + kc) * 512);
      a0 = __builtin_amdgcn_mfma_f32_32x32x16_bf16(Ah[kc], B0, a0, 0, 0, 0);
      a1 = __builtin_amdgcn_mfma_f32_32x32x16_bf16(Ah[kc], B1, a1, 0, 0, 0);
      a2 = __builtin_amdgcn_mfma_f32_32x32x16_bf16(Ah[kc], B2, a2, 0, 0, 0);
      a3 = __builtin_amdgcn_mfma_f32_32x32x16_bf16(Ah[kc], B3, a3, 0, 0, 0);
    }
    const int colb = wc0 + c * 128 + (l31 << 2);
    const float4 q4 = *(const float4*)(embsq + colb);
    #pragma unroll
    for (int k = 0; k < 16; ++k) {
      float s0 = fmaf(2.f, a0[k], -q4.x);
      float s1 = fmaf(2.f, a1[k], -q4.y);
      float s2 = fmaf(2.f, a2[k], -q4.z);
      float s3 = fmaf(2.f, a3[k], -q4.w);
      int row = (k & 3) + 8 * (k >> 2) + 4 * h;
      int nr  = (row < 16) ? (n0 + row) : (HALF + n0 + row - 16);
      h4v hv;
      hv[0] = (_Float16)s0; hv[1] = (_Float16)s1;
      hv[2] = (_Float16)s2; hv[3] = (_Float16)s3;
      *(h4v*)(sbuf + (size_t)nr * KC + colb) = hv;
      es[k] += __expf(s0) + __expf(s1) + __expf(s2) + __expf(s3);
      unsigned u, key;
      u = __float_as_uint(s0); u ^= (unsigned)((int)u >> 31) | 0x80000000u;
      key = (u & 0xFFFFF800u) | (unsigned)(2047 - colb);
      ak[k] = key > ak[k] ? key : ak[k];
      u = __float_as_uint(s1); u ^= (unsigned)((int)u >> 31) | 0x80000000u;
      key = (u & 0xFFFFF800u) | (unsigned)(2046 - colb);
      ak[k] = key > ak[k] ? key : ak[k];
      u = __float_as_uint(s2); u ^= (unsigned)((int)u >> 31) | 0x80000000u;
      key = (u & 0xFFFFF800u) | (unsigned)(2045 - colb);
      ak[k] = key > ak[k] ? key : ak[k];
      u = __float_as_uint(s3); u ^= (unsigned)((int)u >> 31) | 0x80000000u;
      key = (u & 0xFFFFF800u) | (unsigned)(2044 - colb);
      ak[k] = key > ak[k] ? key : ak[k];
    }
  }

  // reduce S and key over l31 (h halves are distinct rows)
  #pragma unroll
  for (int k = 0; k < 16; ++k) {
    #pragma unroll
    for (int m = 1; m < 32; m <<= 1) {
      es[k] += __shfl_xor(es[k], m);
      unsigned o = (unsigned)__shfl_xor((int)ak[k], m);
      ak[k] = o > ak[k] ? o : ak[k];
    }
  }
  if (l31 == 0) {
    #pragma unroll
    for (int k = 0; k < 16; ++k) {
      int row = (k & 3) + 8 * (k >> 2) + 4 * h;
      red_es[row][w] = es[k];
      red_ak[row][w] = ak[k];
    }
  }
  __syncthreads();
  if (tid < 32) {
    float S = red_es[tid][0] + red_es[tid][1] + red_es[tid][2] + red_es[tid][3];
    unsigned K0 = red_ak[tid][0] > red_ak[tid][1] ? red_ak[tid][0] : red_ak[tid][1];
    unsigned K1 = red_ak[tid][2] > red_ak[tid][3] ? red_ak[tid][2] : red_ak[tid][3];
    unsigned K = K0 > K1 ? K0 : K1;
    int n = (tid < 16) ? (n0 + tid) : (HALF + n0 + tid - 16);
    Sinv[n] = 1.f / S;
    int ci = 2047 - (int)(K & 0x7FFu);
    g_idx[tid] = ci;
    minidx[n] = ci;
  }
  __syncthreads();

  // q_loss partial: (emb[argmin] - z)^2 over 32 rows x 64 dims
  float sq = 0.f;
  #pragma unroll
  for (int p = 0; p < 8; ++p) {
    int idx = tid + (p << 8);
    int row = idx >> 6, d = idx & 63;
    int n = (row < 16) ? (n0 + row) : (HALF + n0 + row - 16);
    float diff = emb[g_idx[row] * 64 + d] - zf[n * 64 + d];
    sq = fmaf(diff, diff, sq);
  }
  sq = wave_red_sum(sq);
  if (lane == 0) red_q[w] = sq;
  __syncthreads();
  if (tid == 0)
    atomicAdd(&accums[2], (double)(red_q[0] + red_q[1] + red_q[2] + red_q[3]));
}

// ---------- writeback: single sbuf read, p = exp(s)*Sinv, dense stores, JSD/entropy ----------
// 2048 blocks x 256 thr; block = 8 pairs x 2048 cols; thread owns cols {tid + 256c}.
__global__ __launch_bounds__(256) void write_kernel(
    const _Float16* __restrict__ sbuf, const float* __restrict__ Sinv,
    float* __restrict__ probs, double* __restrict__ accums)
{
  __shared__ float sinv_s[16];
  __shared__ float red_sc[2][4];

  const int tid = threadIdx.x;
  const int w = tid >> 6, lane = tid & 63;
  const int q0 = blockIdx.x * 8;

  if (tid < 16) sinv_s[tid] = (tid < 8) ? Sinv[q0 + tid] : Sinv[HALF + q0 + tid - 8];
  __syncthreads();

  float tpl = 0.f, klm = 0.f;
  #pragma unroll
  for (int i = 0; i < 8; ++i) {
    const float invL = sinv_s[i], invH = sinv_s[i + 8];
    const _Float16* sl = sbuf + (size_t)(q0 + i) * KC;
    const _Float16* sh = sbuf + (size_t)(HALF + q0 + i) * KC;
    float* pl = probs + (size_t)(q0 + i) * KC;
    float* ph = probs + (size_t)(HALF + q0 + i) * KC;
    #pragma unroll
    for (int c = 0; c < 8; ++c) {
      int col = tid + (c << 8);
      float p1 = __expf((float)sl[col]) * invL;
      float p2 = __expf((float)sh[col]) * invH;
      __builtin_nontemporal_store(p1, pl + col);
      __builtin_nontemporal_store(p2, ph + col);
      tpl += p1 * __logf(p1 + EPSF) + p2 * __logf(p2 + EPSF);
      float ps = p1 + p2;
      klm = fmaf(ps, __logf(fmaf(0.5f, ps, EPSF)), klm);
    }
  }
  tpl = wave_red_sum(tpl);
  klm = wave_red_sum(klm);
  if (lane == 0) { red_sc[0][w] = tpl - klm; red_sc[1][w] = -tpl; }
  __syncthreads();
  if (tid == 0) {
    float A = 0.f, B = 0.f;
    #pragma unroll
    for (int i = 0; i < 4; ++i) { A += red_sc[0][i]; B += red_sc[1][i]; }
    atomicAdd(&accums[0], (double)A);   // sum over pairs (kl1+kl2)
    atomicAdd(&accums[1], (double)B);   // -(sum p ln p) -> entropy
  }
}

// ---------- epilogue: z_q_out transpose-gather + scalar finalize ----------
__global__ __launch_bounds__(256) void zqout_kernel(const float* __restrict__ emb,
                                                    const int* __restrict__ minidx,
                                                    const double* __restrict__ accums,
                                                    float* __restrict__ out) {
  const int o  = blockIdx.x * 256 + threadIdx.x;
  const int w_ = o & 63;
  const int hh = (o >> 6) & 63;
  const int d  = (o >> 12) & 63;
  const int b  = o >> 18;
  const int n  = b * 4096 + hh * 64 + w_;
  out[o] = emb[minidx[n] * 64 + d];
  if (o == 0) {
    out[2097152] = (float)(1.25 * accums[2] / 2097152.0);   // q_loss
    out[2097153] = (float)(0.5 * accums[0] / 16384.0);      // jsd
    out[2097154] = (float)(accums[1] / 32768.0);            // entropy
  }
}

extern "C" void kernel_launch(void* const* d_in, const int* in_sizes, int n_in,
                              void* d_out, int out_size, void* d_ws, size_t ws_size,
                              hipStream_t stream) {
  const float* z   = (const float*)d_in[0];
  const float* emb = (const float*)d_in[1];
  float* out = (float*)d_out;

  float*          zf     = (float*)d_ws;                      // 8 MB
  unsigned short* ebh    = (unsigned short*)(zf + 2097152);   // 256 KB
  float*          embsq  = (float*)(ebh + 131072);            // 8 KB
  int*            minidx = (int*)(embsq + 2048);              // 128 KB
  float*          Sinv   = (float*)(minidx + 32768);          // 128 KB
  double*         accums = (double*)(Sinv + 32768);           // 32 B
  size_t used = (size_t)((char*)(accums + 4) - (char*)d_ws);
  _Float16* sbuf = (_Float16*)((char*)d_ws + ((used + 255) & ~(size_t)255)); // 134 MB

  float* probs = out + 2097155;

  prep_kernel <<<520,  256, 0, stream>>>(z, emb, zf, ebh, embsq, accums);
  score_kernel<<<1024, 256, 0, stream>>>(zf, ebh, embsq, emb, sbuf, Sinv, minidx, accums);
  write_kernel<<<2048, 256, 0, stream>>>(sbuf, Sinv, probs, accums);
  zqout_kernel<<<8192, 256, 0, stream>>>(emb, minidx, accums, out);
}

// Round 7
// 210.187 us; speedup vs baseline: 1.1517x; 1.0181x over previous
//
#include <hip/hip_runtime.h>
#include <cstdint>
#include <cstddef>

#define EPSF 1e-8f
constexpr int HALF = 16384;
constexpr int KC   = 2048;

typedef __attribute__((ext_vector_type(8)))  short short8v;
typedef __attribute__((ext_vector_type(16))) float f32x16;

__device__ __forceinline__ unsigned short f2bf_rn(float f) {
  unsigned u = __float_as_uint(f);
  return (unsigned short)((u + 0x7fffu + ((u >> 16) & 1u)) >> 16);
}
__device__ __forceinline__ float wave_red_sum(float v) {
  #pragma unroll
  for (int m = 32; m; m >>= 1) v += __shfl_xor(v, m);
  return v;
}
__device__ __forceinline__ f32x16 z16() {
  f32x16 v;
  #pragma unroll
  for (int k = 0; k < 16; ++k) v[k] = 0.f;
  return v;
}

// ---------- prep (merged): blocks 0-511: z transpose; 512-519: emb pack ----------
// ebh fragment order (q-major cols): col C -> tile=C>>7, u=C&127, q=u>>5, l31=u&31;
// K index k=kc*16+h*8+j -> flat = tile*8192 + (q*4+kc)*512 + h*256 + l31*8 + j.
// A wave's B-load for fixed (q,kc) is 64 lanes x 16B = 1KB dense.
__global__ __launch_bounds__(256) void prep_kernel(const float* __restrict__ z,
    const float* __restrict__ emb, float* __restrict__ zf,
    unsigned short* __restrict__ ebh, float* __restrict__ embsq,
    double* __restrict__ accums) {
  const int tid = threadIdx.x;
  if (blockIdx.x < 512) {
    __shared__ float t[64][65];
    const int bi  = blockIdx.x >> 6;
    const int hw0 = (blockIdx.x & 63) << 6;
    for (int i = tid; i < 4096; i += 256) {
      int d = i >> 6, j = i & 63;
      t[d][j] = z[bi * 262144 + d * 4096 + hw0 + j];
    }
    __syncthreads();
    for (int i = tid; i < 4096; i += 256) {
      int j = i >> 6, d = i & 63;
      zf[(bi * 4096 + hw0 + j) * 64 + d] = t[d][j];
    }
  } else {
    if (blockIdx.x == 512 && tid < 4) accums[tid] = 0.0;
    const int c = (blockIdx.x - 512) * 256 + tid;
    const int tile = c >> 7, u = c & 127, q = u >> 5, l31c = u & 31;
    unsigned short* base = ebh + tile * 8192 + l31c * 8;
    float s = 0.f;
    #pragma unroll
    for (int kc = 0; kc < 4; ++kc) {
      unsigned short* seg = base + (q * 4 + kc) * 512;
      #pragma unroll
      for (int j = 0; j < 16; ++j) {
        float v = emb[c * 64 + kc * 16 + j];
        seg[(j >> 3) * 256 + (j & 7)] = f2bf_rn(v);
        s = fmaf(v, v, s);
      }
    }
    embsq[c] = s;
  }
}

// Shared MFMA chunk: computes a0..a3 for chunk c (cols wc0+c*128 + q*32 + l31)
#define MFMA_CHUNK(c_)                                                         \
  {                                                                            \
    const unsigned short* bp = ebh + (size_t)(wtile + (c_)) * 8192 + h * 256 + l31 * 8; \
    _Pragma("unroll")                                                          \
    for (int kc = 0; kc < 4; ++kc) {                                           \
      short8v B0 = *(const short8v*)(bp + (0 * 4 + kc) * 512);                 \
      short8v B1 = *(const short8v*)(bp + (1 * 4 + kc) * 512);                 \
      short8v B2 = *(const short8v*)(bp + (2 * 4 + kc) * 512);                 \
      short8v B3 = *(const short8v*)(bp + (3 * 4 + kc) * 512);                 \
      a0 = __builtin_amdgcn_mfma_f32_32x32x16_bf16(Ah[kc], B0, a0, 0, 0, 0);   \
      a1 = __builtin_amdgcn_mfma_f32_32x32x16_bf16(Ah[kc], B1, a1, 0, 0, 0);   \
      a2 = __builtin_amdgcn_mfma_f32_32x32x16_bf16(Ah[kc], B2, a2, 0, 0, 0);   \
      a3 = __builtin_amdgcn_mfma_f32_32x32x16_bf16(Ah[kc], B3, a3, 0, 0, 0);   \
    }                                                                          \
  }

#define LOAD_AFRAG                                                             \
  short8v Ah[4];                                                               \
  {                                                                            \
    const int an = (l31 < 16) ? (n0 + l31) : (HALF + n0 + l31 - 16);           \
    const float* zrow = zf + an * 64;                                          \
    _Pragma("unroll")                                                          \
    for (int kc = 0; kc < 4; ++kc)                                             \
      _Pragma("unroll")                                                        \
      for (int j = 0; j < 8; ++j)                                              \
        Ah[kc][j] = (short)f2bf_rn(zrow[kc * 16 + h * 8 + j]);                 \
  }

// ---------- pass A: S = sum exp(s), argmax, q_loss. No score stores. ----------
// 1024 blocks x 256 thr; block = 16 pairs (32 rows) x 2048 cols; wave w: 512 cols.
__global__ __launch_bounds__(256, 3) void sum_kernel(
    const float* __restrict__ zf, const unsigned short* __restrict__ ebh,
    const float* __restrict__ embsq, const float* __restrict__ emb,
    float* __restrict__ Sinv, int* __restrict__ minidx, double* __restrict__ accums)
{
  __shared__ float    red_es[32][4];
  __shared__ unsigned red_ak[32][4];
  __shared__ int      g_idx[32];
  __shared__ float    red_q[4];

  const int tid = threadIdx.x;
  const int w = tid >> 6, lane = tid & 63;
  const int l31 = lane & 31, h = lane >> 5;
  const int n0 = blockIdx.x * 16;
  const int wc0 = w * 512;
  const int wtile = w * 4;

  LOAD_AFRAG

  float    es[16];
  unsigned ak[16];
  #pragma unroll
  for (int k = 0; k < 16; ++k) { es[k] = 0.f; ak[k] = 0u; }

  #pragma unroll
  for (int c = 0; c < 4; ++c) {
    f32x16 a0 = z16(), a1 = z16(), a2 = z16(), a3 = z16();
    MFMA_CHUNK(c)
    const int cb = wc0 + c * 128 + l31;
    const float qv0 = embsq[cb];
    const float qv1 = embsq[cb + 32];
    const float qv2 = embsq[cb + 64];
    const float qv3 = embsq[cb + 96];
    const unsigned ki0 = (unsigned)(2047 - cb);
    #pragma unroll
    for (int k = 0; k < 16; ++k) {
      float s0 = fmaf(2.f, a0[k], -qv0);
      float s1 = fmaf(2.f, a1[k], -qv1);
      float s2 = fmaf(2.f, a2[k], -qv2);
      float s3 = fmaf(2.f, a3[k], -qv3);
      es[k] += __expf(s0) + __expf(s1) + __expf(s2) + __expf(s3);
      unsigned u, key;
      u = __float_as_uint(s0); u ^= (unsigned)((int)u >> 31) | 0x80000000u;
      key = (u & 0xFFFFF800u) | ki0;        ak[k] = key > ak[k] ? key : ak[k];
      u = __float_as_uint(s1); u ^= (unsigned)((int)u >> 31) | 0x80000000u;
      key = (u & 0xFFFFF800u) | (ki0 - 32); ak[k] = key > ak[k] ? key : ak[k];
      u = __float_as_uint(s2); u ^= (unsigned)((int)u >> 31) | 0x80000000u;
      key = (u & 0xFFFFF800u) | (ki0 - 64); ak[k] = key > ak[k] ? key : ak[k];
      u = __float_as_uint(s3); u ^= (unsigned)((int)u >> 31) | 0x80000000u;
      key = (u & 0xFFFFF800u) | (ki0 - 96); ak[k] = key > ak[k] ? key : ak[k];
    }
  }

  // reduce S and key over l31 (h halves are distinct rows)
  #pragma unroll
  for (int k = 0; k < 16; ++k) {
    #pragma unroll
    for (int m = 1; m < 32; m <<= 1) {
      es[k] += __shfl_xor(es[k], m);
      unsigned o = (unsigned)__shfl_xor((int)ak[k], m);
      ak[k] = o > ak[k] ? o : ak[k];
    }
  }
  if (l31 == 0) {
    #pragma unroll
    for (int k = 0; k < 16; ++k) {
      int row = (k & 3) + 8 * (k >> 2) + 4 * h;
      red_es[row][w] = es[k];
      red_ak[row][w] = ak[k];
    }
  }
  __syncthreads();
  if (tid < 32) {
    float S = red_es[tid][0] + red_es[tid][1] + red_es[tid][2] + red_es[tid][3];
    unsigned K0 = red_ak[tid][0] > red_ak[tid][1] ? red_ak[tid][0] : red_ak[tid][1];
    unsigned K1 = red_ak[tid][2] > red_ak[tid][3] ? red_ak[tid][2] : red_ak[tid][3];
    unsigned K = K0 > K1 ? K0 : K1;
    int n = (tid < 16) ? (n0 + tid) : (HALF + n0 + tid - 16);
    Sinv[n] = 1.f / S;
    int ci = 2047 - (int)(K & 0x7FFu);
    g_idx[tid] = ci;
    minidx[n] = ci;
  }
  __syncthreads();

  // q_loss partial: (emb[argmin] - z)^2 over 32 rows x 64 dims
  float sq = 0.f;
  #pragma unroll
  for (int p = 0; p < 8; ++p) {
    int idx = tid + (p << 8);
    int row = idx >> 6, d = idx & 63;
    int n = (row < 16) ? (n0 + row) : (HALF + n0 + row - 16);
    float diff = emb[g_idx[row] * 64 + d] - zf[n * 64 + d];
    sq = fmaf(diff, diff, sq);
  }
  sq = wave_red_sum(sq);
  if (lane == 0) red_q[w] = sq;
  __syncthreads();
  if (tid == 0)
    atomicAdd(&accums[2], (double)(red_q[0] + red_q[1] + red_q[2] + red_q[3]));
}

// ---------- pass B: MFMA recompute, p = exp(s)*Sinv, dense dword stores, JSD ----------
__global__ __launch_bounds__(256, 3) void write_kernel(
    const float* __restrict__ zf, const unsigned short* __restrict__ ebh,
    const float* __restrict__ embsq, const float* __restrict__ Sinv,
    float* __restrict__ probs, double* __restrict__ accums)
{
  __shared__ float sinv_lds[32];
  __shared__ float red_sc[2][4];

  const int tid = threadIdx.x;
  const int w = tid >> 6, lane = tid & 63;
  const int l31 = lane & 31, h = lane >> 5;
  const int n0 = blockIdx.x * 16;
  const int wc0 = w * 512;
  const int wtile = w * 4;

  if (tid < 32) {
    int n = (tid < 16) ? (n0 + tid) : (HALF + n0 + tid - 16);
    sinv_lds[tid] = Sinv[n];
  }
  __syncthreads();

  LOAD_AFRAG

  float vinv[16];
  int   nrow[16];
  #pragma unroll
  for (int k = 0; k < 16; ++k) {
    int row = (k & 3) + 8 * (k >> 2) + 4 * h;
    vinv[k] = sinv_lds[row];
    nrow[k] = (row < 16) ? (n0 + row) : (HALF + n0 + row - 16);
  }

  float tpl = 0.f, klm = 0.f;
  #pragma unroll
  for (int c = 0; c < 4; ++c) {
    f32x16 a0 = z16(), a1 = z16(), a2 = z16(), a3 = z16();
    MFMA_CHUNK(c)
    const int cb = wc0 + c * 128 + l31;
    const float qv0 = embsq[cb];
    const float qv1 = embsq[cb + 32];
    const float qv2 = embsq[cb + 64];
    const float qv3 = embsq[cb + 96];
    #pragma unroll
    for (int k = 0; k < 16; ++k) {
      a0[k] = __expf(fmaf(2.f, a0[k], -qv0)) * vinv[k];
      a1[k] = __expf(fmaf(2.f, a1[k], -qv1)) * vinv[k];
      a2[k] = __expf(fmaf(2.f, a2[k], -qv2)) * vinv[k];
      a3[k] = __expf(fmaf(2.f, a3[k], -qv3)) * vinv[k];
    }
    // dense dword stores: per instruction, 32 lanes cover 128B x 2 rows
    #pragma unroll
    for (int k = 0; k < 16; ++k) {
      float* pr = probs + (size_t)nrow[k] * KC + cb;
      pr[0]  = a0[k];
      pr[32] = a1[k];
      pr[64] = a2[k];
      pr[96] = a3[k];
    }
    // JSD/entropy partials: pair rows are regs (k, k+8)
    #pragma unroll
    for (int k = 0; k < 8; ++k) {
      float p1, p2, ps;
      p1 = a0[k]; p2 = a0[k + 8];
      tpl += p1 * __logf(p1 + EPSF) + p2 * __logf(p2 + EPSF);
      ps = p1 + p2; klm = fmaf(ps, __logf(fmaf(0.5f, ps, EPSF)), klm);
      p1 = a1[k]; p2 = a1[k + 8];
      tpl += p1 * __logf(p1 + EPSF) + p2 * __logf(p2 + EPSF);
      ps = p1 + p2; klm = fmaf(ps, __logf(fmaf(0.5f, ps, EPSF)), klm);
      p1 = a2[k]; p2 = a2[k + 8];
      tpl += p1 * __logf(p1 + EPSF) + p2 * __logf(p2 + EPSF);
      ps = p1 + p2; klm = fmaf(ps, __logf(fmaf(0.5f, ps, EPSF)), klm);
      p1 = a3[k]; p2 = a3[k + 8];
      tpl += p1 * __logf(p1 + EPSF) + p2 * __logf(p2 + EPSF);
      ps = p1 + p2; klm = fmaf(ps, __logf(fmaf(0.5f, ps, EPSF)), klm);
    }
  }

  tpl = wave_red_sum(tpl);
  klm = wave_red_sum(klm);
  if (lane == 0) { red_sc[0][w] = tpl - klm; red_sc[1][w] = -tpl; }
  __syncthreads();
  if (tid == 0) {
    float A = 0.f, B = 0.f;
    #pragma unroll
    for (int i = 0; i < 4; ++i) { A += red_sc[0][i]; B += red_sc[1][i]; }
    atomicAdd(&accums[0], (double)A);   // sum over pairs (kl1+kl2)
    atomicAdd(&accums[1], (double)B);   // -(sum p ln p) -> entropy
  }
}

// ---------- epilogue: z_q_out transpose-gather + scalar finalize ----------
__global__ __launch_bounds__(256) void zqout_kernel(const float* __restrict__ emb,
                                                    const int* __restrict__ minidx,
                                                    const double* __restrict__ accums,
                                                    float* __restrict__ out) {
  const int o  = blockIdx.x * 256 + threadIdx.x;
  const int w_ = o & 63;
  const int hh = (o >> 6) & 63;
  const int d  = (o >> 12) & 63;
  const int b  = o >> 18;
  const int n  = b * 4096 + hh * 64 + w_;
  out[o] = emb[minidx[n] * 64 + d];
  if (o == 0) {
    out[2097152] = (float)(1.25 * accums[2] / 2097152.0);   // q_loss
    out[2097153] = (float)(0.5 * accums[0] / 16384.0);      // jsd
    out[2097154] = (float)(accums[1] / 32768.0);            // entropy
  }
}

extern "C" void kernel_launch(void* const* d_in, const int* in_sizes, int n_in,
                              void* d_out, int out_size, void* d_ws, size_t ws_size,
                              hipStream_t stream) {
  const float* z   = (const float*)d_in[0];
  const float* emb = (const float*)d_in[1];
  float* out = (float*)d_out;

  float*          zf     = (float*)d_ws;                      // 8 MB
  unsigned short* ebh    = (unsigned short*)(zf + 2097152);   // 256 KB
  float*          embsq  = (float*)(ebh + 131072);            // 8 KB
  int*            minidx = (int*)(embsq + 2048);              // 128 KB
  float*          Sinv   = (float*)(minidx + 32768);          // 128 KB
  double*         accums = (double*)(Sinv + 32768);           // 32 B

  float* probs = out + 2097155;

  prep_kernel <<<520,  256, 0, stream>>>(z, emb, zf, ebh, embsq, accums);
  sum_kernel  <<<1024, 256, 0, stream>>>(zf, ebh, embsq, emb, Sinv, minidx, accums);
  write_kernel<<<1024, 256, 0, stream>>>(zf, ebh, embsq, Sinv, probs, accums);
  zqout_kernel<<<8192, 256, 0, stream>>>(emb, minidx, accums, out);
}

// Round 9
// 153.324 us; speedup vs baseline: 1.5788x; 1.3709x over previous
//
#include <hip/hip_runtime.h>
#include <cstdint>
#include <cstddef>

#define EPSF 1e-8f
constexpr int HALF = 16384;
constexpr int KC   = 2048;

#define L2E   1.4426950408889634f
#define A_SC  2.8853900817779268f   /* 2*log2(e) */
#define SHIFT 0.25f
#define LN2   0.6931471805599453f

typedef __attribute__((ext_vector_type(8)))  short short8v;
typedef __attribute__((ext_vector_type(16))) float f32x16;

__device__ __forceinline__ unsigned short f2bf_rn(float f) {
  unsigned u = __float_as_uint(f);
  return (unsigned short)((u + 0x7fffu + ((u >> 16) & 1u)) >> 16);
}
__device__ __forceinline__ float wave_red_sum(float v) {
  #pragma unroll
  for (int m = 32; m; m >>= 1) v += __shfl_xor(v, m);
  return v;
}
__device__ __forceinline__ f32x16 z16() {
  f32x16 v;
  #pragma unroll
  for (int k = 0; k < 16; ++k) v[k] = 0.f;
  return v;
}

// ---------- prep (merged): blocks 0-511: z transpose; 512-519: emb pack ----------
// ebh fragment order (q-major cols): col C -> tile=C>>7, u=C&127, q=u>>5, l31=u&31;
// K index k=kc*16+h*8+j -> flat = tile*8192 + (q*4+kc)*512 + h*256 + l31*8 + j.
__global__ __launch_bounds__(256) void prep_kernel(const float* __restrict__ z,
    const float* __restrict__ emb, float* __restrict__ zf,
    unsigned short* __restrict__ ebh, float* __restrict__ embsq2,
    double* __restrict__ accums) {
  const int tid = threadIdx.x;
  if (blockIdx.x < 512) {
    __shared__ float t[64][65];
    const int bi  = blockIdx.x >> 6;
    const int hw0 = (blockIdx.x & 63) << 6;
    for (int i = tid; i < 4096; i += 256) {
      int d = i >> 6, j = i & 63;
      t[d][j] = z[bi * 262144 + d * 4096 + hw0 + j];
    }
    __syncthreads();
    for (int i = tid; i < 4096; i += 256) {
      int j = i >> 6, d = i & 63;
      zf[(bi * 4096 + hw0 + j) * 64 + d] = t[d][j];
    }
  } else {
    if (blockIdx.x == 512 && tid < 4) accums[tid] = 0.0;
    const int c = (blockIdx.x - 512) * 256 + tid;
    const int tile = c >> 7, u = c & 127, q = u >> 5, l31c = u & 31;
    unsigned short* base = ebh + tile * 8192 + l31c * 8;
    float s = 0.f;
    #pragma unroll
    for (int kc = 0; kc < 4; ++kc) {
      unsigned short* seg = base + (q * 4 + kc) * 512;
      #pragma unroll
      for (int j = 0; j < 16; ++j) {
        float v = emb[c * 64 + kc * 16 + j];
        seg[(j >> 3) * 256 + (j & 7)] = f2bf_rn(v);
        s = fmaf(v, v, s);
      }
    }
    embsq2[c] = SHIFT - L2E * s;   // s2 = fma(A_SC, dot, embsq2) = log2e*(2dot-||e||^2)+SHIFT
  }
}

// Shared MFMA chunk: computes a0..a3 (dots) for chunk c (cols wc0+c*128 + q*32 + l31)
#define MFMA_CHUNK(c_)                                                         \
  {                                                                            \
    const unsigned short* bp = ebh + (size_t)(wtile + (c_)) * 8192 + h * 256 + l31 * 8; \
    _Pragma("unroll")                                                          \
    for (int kc = 0; kc < 4; ++kc) {                                           \
      short8v B0 = *(const short8v*)(bp + (0 * 4 + kc) * 512);                 \
      short8v B1 = *(const short8v*)(bp + (1 * 4 + kc) * 512);                 \
      short8v B2 = *(const short8v*)(bp + (2 * 4 + kc) * 512);                 \
      short8v B3 = *(const short8v*)(bp + (3 * 4 + kc) * 512);                 \
      a0 = __builtin_amdgcn_mfma_f32_32x32x16_bf16(Ah[kc], B0, a0, 0, 0, 0);   \
      a1 = __builtin_amdgcn_mfma_f32_32x32x16_bf16(Ah[kc], B1, a1, 0, 0, 0);   \
      a2 = __builtin_amdgcn_mfma_f32_32x32x16_bf16(Ah[kc], B2, a2, 0, 0, 0);   \
      a3 = __builtin_amdgcn_mfma_f32_32x32x16_bf16(Ah[kc], B3, a3, 0, 0, 0);   \
    }                                                                          \
  }

#define LOAD_AFRAG                                                             \
  short8v Ah[4];                                                               \
  {                                                                            \
    const int an = (l31 < 16) ? (n0 + l31) : (HALF + n0 + l31 - 16);           \
    const float* zrow = zf + an * 64;                                          \
    _Pragma("unroll")                                                          \
    for (int kc = 0; kc < 4; ++kc)                                             \
      _Pragma("unroll")                                                        \
      for (int j = 0; j < 8; ++j)                                              \
        Ah[kc][j] = (short)f2bf_rn(zrow[kc * 16 + h * 8 + j]);                 \
  }

// ---------- pass A: S' = sum exp2(s2), packed argmax, q_loss via identity ----------
// 1024 blocks x 256 thr; block = 16 pairs (32 rows) x 2048 cols; wave w: 512 cols.
__global__ __launch_bounds__(256, 3) void sum_kernel(
    const float* __restrict__ zf, const unsigned short* __restrict__ ebh,
    const float* __restrict__ embsq2, float* __restrict__ Sinv,
    int* __restrict__ minidx, double* __restrict__ accums)
{
  __shared__ float    red_es[32][4];
  __shared__ unsigned red_ak[32][4];
  __shared__ float    red_q[4];
  __shared__ float    s_smax;

  const int tid = threadIdx.x;
  const int w = tid >> 6, lane = tid & 63;
  const int l31 = lane & 31, h = lane >> 5;
  const int n0 = blockIdx.x * 16;
  const int wc0 = w * 512;
  const int wtile = w * 4;

  LOAD_AFRAG

  float    es[16];
  unsigned ak[16];
  #pragma unroll
  for (int k = 0; k < 16; ++k) { es[k] = 0.f; ak[k] = 0u; }

  #pragma unroll
  for (int c = 0; c < 4; ++c) {
    f32x16 a0 = z16(), a1 = z16(), a2 = z16(), a3 = z16();
    MFMA_CHUNK(c)
    const int cb = wc0 + c * 128 + l31;
    const float q0 = embsq2[cb];
    const float q1 = embsq2[cb + 32];
    const float q2 = embsq2[cb + 64];
    const float q3 = embsq2[cb + 96];
    const unsigned ki0 = (unsigned)(2047 - cb);
    #pragma unroll
    for (int k = 0; k < 16; ++k) {
      float s0 = fmaf(A_SC, a0[k], q0);   // s2 > 0 always (SHIFT=0.25 >> |log2e*s|)
      float s1 = fmaf(A_SC, a1[k], q1);
      float s2 = fmaf(A_SC, a2[k], q2);
      float s3 = fmaf(A_SC, a3[k], q3);
      es[k] += __builtin_exp2f(s0) + __builtin_exp2f(s1) +
               __builtin_exp2f(s2) + __builtin_exp2f(s3);
      unsigned key;
      key = (__float_as_uint(s0) & 0xFFFFF800u) | ki0;        ak[k] = key > ak[k] ? key : ak[k];
      key = (__float_as_uint(s1) & 0xFFFFF800u) | (ki0 - 32); ak[k] = key > ak[k] ? key : ak[k];
      key = (__float_as_uint(s2) & 0xFFFFF800u) | (ki0 - 64); ak[k] = key > ak[k] ? key : ak[k];
      key = (__float_as_uint(s3) & 0xFFFFF800u) | (ki0 - 96); ak[k] = key > ak[k] ? key : ak[k];
    }
  }

  // reduce S and key over l31 (h halves are distinct rows)
  #pragma unroll
  for (int k = 0; k < 16; ++k) {
    #pragma unroll
    for (int m = 1; m < 32; m <<= 1) {
      es[k] += __shfl_xor(es[k], m);
      unsigned o = (unsigned)__shfl_xor((int)ak[k], m);
      ak[k] = o > ak[k] ? o : ak[k];
    }
  }
  if (l31 == 0) {
    #pragma unroll
    for (int k = 0; k < 16; ++k) {
      int row = (k & 3) + 8 * (k >> 2) + 4 * h;
      red_es[row][w] = es[k];
      red_ak[row][w] = ak[k];
    }
  }
  __syncthreads();
  if (tid < 32) {
    float S = red_es[tid][0] + red_es[tid][1] + red_es[tid][2] + red_es[tid][3];
    unsigned K0 = red_ak[tid][0] > red_ak[tid][1] ? red_ak[tid][0] : red_ak[tid][1];
    unsigned K1 = red_ak[tid][2] > red_ak[tid][3] ? red_ak[tid][2] : red_ak[tid][3];
    unsigned K = K0 > K1 ? K0 : K1;
    int n = (tid < 16) ? (n0 + tid) : (HALF + n0 + tid - 16);
    Sinv[n] = 1.f / S;
    minidx[n] = 2047 - (int)(K & 0x7FFu);
    // s_true at argmax (natural-log scale of the ORIGINAL s = 2 z.e - ||e||^2)
    float sm = (__uint_as_float(K & 0xFFFFF800u) - SHIFT) * LN2;
    #pragma unroll
    for (int m = 1; m < 32; m <<= 1) sm += __shfl_xor(sm, m);
    if (tid == 0) s_smax = sm;
  }

  // zsq: sum ||z||^2 over the block's 32 rows (dist_min = ||z||^2 - s_max)
  float sq = 0.f;
  #pragma unroll
  for (int p = 0; p < 8; ++p) {
    int idx = tid + (p << 8);
    int row = idx >> 6, d = idx & 63;
    int n = (row < 16) ? (n0 + row) : (HALF + n0 + row - 16);
    float v = zf[n * 64 + d];
    sq = fmaf(v, v, sq);
  }
  sq = wave_red_sum(sq);
  if (lane == 0) red_q[w] = sq;
  __syncthreads();
  if (tid == 0) {
    float zb = red_q[0] + red_q[1] + red_q[2] + red_q[3];
    atomicAdd(&accums[2], (double)(zb - s_smax));
  }
}

// ---------- pass B: MFMA recompute, p = exp2(s2)*Sinv', dense stores, JSD/entropy ----------
__global__ __launch_bounds__(256, 3) void write_kernel(
    const float* __restrict__ zf, const unsigned short* __restrict__ ebh,
    const float* __restrict__ embsq2, const float* __restrict__ Sinv,
    float* __restrict__ probs, double* __restrict__ accums)
{
  __shared__ float sinv_lds[32];
  __shared__ float red_sc[2][4];
  __shared__ float s_lns;

  const int tid = threadIdx.x;
  const int w = tid >> 6, lane = tid & 63;
  const int l31 = lane & 31, h = lane >> 5;
  const int n0 = blockIdx.x * 16;
  const int wc0 = w * 512;
  const int wtile = w * 4;

  if (tid < 32) {
    int n = (tid < 16) ? (n0 + tid) : (HALF + n0 + tid - 16);
    float si = Sinv[n];
    sinv_lds[tid] = si;
    // sum of ln S' over the block's 32 rows (S' = 1/si)
    float lnS = -LN2 * __log2f(si);
    #pragma unroll
    for (int m = 1; m < 32; m <<= 1) lnS += __shfl_xor(lnS, m);
    if (tid == 0) s_lns = lnS;
  }
  __syncthreads();

  LOAD_AFRAG

  float vinv[16];
  int   poff[16];
  #pragma unroll
  for (int k = 0; k < 16; ++k) {
    int row = (k & 3) + 8 * (k >> 2) + 4 * h;
    vinv[k] = sinv_lds[row];
    int n = (row < 16) ? (n0 + row) : (HALF + n0 + row - 16);
    poff[k] = n * KC;
  }

  float tpl2 = 0.f, klm2 = 0.f;
  #pragma unroll
  for (int c = 0; c < 4; ++c) {
    f32x16 a0 = z16(), a1 = z16(), a2 = z16(), a3 = z16();
    MFMA_CHUNK(c)
    const int cb = wc0 + c * 128 + l31;
    const float q0 = embsq2[cb];
    const float q1 = embsq2[cb + 32];
    const float q2 = embsq2[cb + 64];
    const float q3 = embsq2[cb + 96];
    #pragma unroll
    for (int k = 0; k < 16; ++k) {
      float s0 = fmaf(A_SC, a0[k], q0);
      float s1 = fmaf(A_SC, a1[k], q1);
      float s2 = fmaf(A_SC, a2[k], q2);
      float s3 = fmaf(A_SC, a3[k], q3);
      float p0 = __builtin_exp2f(s0) * vinv[k];
      float p1 = __builtin_exp2f(s1) * vinv[k];
      float p2 = __builtin_exp2f(s2) * vinv[k];
      float p3 = __builtin_exp2f(s3) * vinv[k];
      a0[k] = p0; a1[k] = p1; a2[k] = p2; a3[k] = p3;
      // sum p*s2 (base-2); ln p = LN2*s2 - ln S'  =>  sum p ln p = LN2*tpl2 - sum ln S'
      tpl2 = fmaf(p0, s0, tpl2);
      tpl2 = fmaf(p1, s1, tpl2);
      tpl2 = fmaf(p2, s2, tpl2);
      tpl2 = fmaf(p3, s3, tpl2);
    }
    // dense dword stores: per instruction, 32 lanes cover 128B x 2 rows
    #pragma unroll
    for (int k = 0; k < 16; ++k) {
      float* pr = probs + poff[k] + cb;
      pr[0]  = a0[k];
      pr[32] = a1[k];
      pr[64] = a2[k];
      pr[96] = a3[k];
    }
    // mixture term: pair rows are regs (k, k+8); klm2 = sum ps*log2(ps/2+eps)
    #pragma unroll
    for (int k = 0; k < 8; ++k) {
      float ps;
      ps = a0[k] + a0[k + 8];
      klm2 = fmaf(ps, __log2f(fmaf(0.5f, ps, EPSF)), klm2);
      ps = a1[k] + a1[k + 8];
      klm2 = fmaf(ps, __log2f(fmaf(0.5f, ps, EPSF)), klm2);
      ps = a2[k] + a2[k + 8];
      klm2 = fmaf(ps, __log2f(fmaf(0.5f, ps, EPSF)), klm2);
      ps = a3[k] + a3[k + 8];
      klm2 = fmaf(ps, __log2f(fmaf(0.5f, ps, EPSF)), klm2);
    }
  }

  tpl2 = wave_red_sum(tpl2);
  klm2 = wave_red_sum(klm2);
  if (lane == 0) { red_sc[0][w] = tpl2; red_sc[1][w] = klm2; }
  __syncthreads();
  if (tid == 0) {
    float T = red_sc[0][0] + red_sc[0][1] + red_sc[0][2] + red_sc[0][3];
    float Km = red_sc[1][0] + red_sc[1][1] + red_sc[1][2] + red_sc[1][3];
    // sum_k p ln p over block's 32 rows = LN2*T - sum_rows ln S'
    float spl = LN2 * T - s_lns;
    atomicAdd(&accums[0], (double)(spl - LN2 * Km));  // sum (kl1+kl2) contribution
    atomicAdd(&accums[1], (double)(-spl));            // entropy contribution
  }
}

// ---------- epilogue: z_q_out transpose-gather + scalar finalize ----------
__global__ __launch_bounds__(256) void zqout_kernel(const float* __restrict__ emb,
                                                    const int* __restrict__ minidx,
                                                    const double* __restrict__ accums,
                                                    float* __restrict__ out) {
  const int o  = blockIdx.x * 256 + threadIdx.x;
  const int w_ = o & 63;
  const int hh = (o >> 6) & 63;
  const int d  = (o >> 12) & 63;
  const int b  = o >> 18;
  const int n  = b * 4096 + hh * 64 + w_;
  out[o] = emb[minidx[n] * 64 + d];
  if (o == 0) {
    out[2097152] = (float)(1.25 * accums[2] / 2097152.0);   // q_loss
    out[2097153] = (float)(0.5 * accums[0] / 16384.0);      // jsd
    out[2097154] = (float)(accums[1] / 32768.0);            // entropy
  }
}

extern "C" void kernel_launch(void* const* d_in, const int* in_sizes, int n_in,
                              void* d_out, int out_size, void* d_ws, size_t ws_size,
                              hipStream_t stream) {
  const float* z   = (const float*)d_in[0];
  const float* emb = (const float*)d_in[1];
  float* out = (float*)d_out;

  float*          zf     = (float*)d_ws;                      // 8 MB
  unsigned short* ebh    = (unsigned short*)(zf + 2097152);   // 256 KB
  float*          embsq2 = (float*)(ebh + 131072);            // 8 KB
  int*            minidx = (int*)(embsq2 + 2048);             // 128 KB
  float*          Sinv   = (float*)(minidx + 32768);          // 128 KB
  double*         accums = (double*)(Sinv + 32768);           // 32 B

  float* probs = out + 2097155;

  prep_kernel <<<520,  256, 0, stream>>>(z, emb, zf, ebh, embsq2, accums);
  sum_kernel  <<<1024, 256, 0, stream>>>(zf, ebh, embsq2, Sinv, minidx, accums);
  write_kernel<<<1024, 256, 0, stream>>>(zf, ebh, embsq2, Sinv, probs, accums);
  zqout_kernel<<<8192, 256, 0, stream>>>(emb, minidx, accums, out);
}